// Round 3
// baseline (213.296 us; speedup 1.0000x reference)
//
#include <hip/hip_runtime.h>
#include <hip/hip_bf16.h>

// Conv2d 3x3 s1p1: x(32,128,56,56) f32, w(256,128,3,3) f32, bias(256) -> (32,256,56,56) f32.
// R4 (2nd resubmit; rounds 1-2 hit GPUAcquisitionTimeout — no data):
// conv_main K-loop rebuilt as counted-vmcnt pipeline (T3+T4): BK=32, 4 LDS buffers
// (depth-3 prefetch), ONE raw s_barrier per stage, s_waitcnt vmcnt(8) (never 0 in loop),
// setprio around MFMA cluster (T5). Tile/fragment/swizzle semantics identical to R3.
// prep_x / prep_w unchanged.

#define CIN   128
#define HH    56
#define WW    56
#define COUT  256
#define HW    3136
#define NIMG  32
#define NP    (NIMG * HW)            // 100352 = 784 * 128
#define XPW   58
#define XPIX  (XPW * XPW)            // 3364
#define XPAD_BYTES (NIMG * XPIX * CIN * 2)   // 27,566,080
#define WT_OFF     XPAD_BYTES

typedef __bf16 bf16x8 __attribute__((ext_vector_type(8)));
typedef float  f32x4  __attribute__((ext_vector_type(4)));

#define GLD16(g, l) __builtin_amdgcn_global_load_lds( \
    (const __attribute__((address_space(1))) void*)(g), \
    (__attribute__((address_space(3))) void*)(l), 16, 0, 0)

__device__ __forceinline__ unsigned pack_bf16(float a, float b) {
    return (__float_as_uint(b) & 0xFFFF0000u) | (__float_as_uint(a) >> 16);
}

// ---- pre-pass 1: x NCHW f32 -> xpad NHWC bf16 with 1-px halo; writes own halo zeros.
__global__ __launch_bounds__(128) void prep_x(const float* __restrict__ x,
                                              __hip_bfloat16* __restrict__ xp) {
    __shared__ unsigned short t[HH * CIN];   // [x][ci], 14336 B
    const int b  = blockIdx.x;               // 32*56
    const int n  = b / HH;
    const int y  = b - n * HH;
    const int ci = threadIdx.x;              // 0..127

    const float* src = x + ((size_t)(n * CIN + ci) * HW) + y * WW;
    #pragma unroll
    for (int j = 0; j < 14; ++j) {           // 56 floats, per-lane contiguous stream
        const float4 v = ((const float4*)src)[j];
        t[(4 * j + 0) * CIN + ci] = (unsigned short)(__float_as_uint(v.x) >> 16);
        t[(4 * j + 1) * CIN + ci] = (unsigned short)(__float_as_uint(v.y) >> 16);
        t[(4 * j + 2) * CIN + ci] = (unsigned short)(__float_as_uint(v.z) >> 16);
        t[(4 * j + 3) * CIN + ci] = (unsigned short)(__float_as_uint(v.w) >> 16);
    }

    const uint4 z = make_uint4(0, 0, 0, 0);
    if (ci < 32) {
        const int side = ci >> 4;            // 0 = x'=0, 1 = x'=57
        const int j    = ci & 15;
        ((uint4*)(xp + ((size_t)n * XPIX + (y + 1) * XPW + side * 57) * CIN))[j] = z;
    }
    if (y == 0)
        for (int j = ci; j < 928; j += 128)  // row 0: 58*128 bf16 = 928 uint4
            ((uint4*)(xp + (size_t)n * XPIX * CIN))[j] = z;
    if (y == HH - 1)
        for (int j = ci; j < 928; j += 128)  // row 57
            ((uint4*)(xp + ((size_t)n * XPIX + 57 * XPW) * CIN))[j] = z;

    __syncthreads();

    uint4* dst = (uint4*)(xp + ((size_t)n * XPIX + (y + 1) * XPW + 1) * CIN);
    const uint4* lsrc = (const uint4*)t;
    #pragma unroll
    for (int j = 0; j < 7; ++j)
        dst[j * 128 + ci] = lsrc[j * 128 + ci];
}

// ---- pre-pass 2: w (co,ci,3,3) f32 -> Wt[tap][co][ci] bf16
__global__ __launch_bounds__(256) void prep_w(const float* __restrict__ w,
                                              __hip_bfloat16* __restrict__ wt) {
    const int co = blockIdx.x * 2 + (threadIdx.x >> 7);
    const int ci = threadIdx.x & 127;
    const float* src = w + (size_t)(co * CIN + ci) * 9;
    #pragma unroll
    for (int tp = 0; tp < 9; ++tp)
        wt[(size_t)tp * (COUT * CIN) + co * CIN + ci] = __float2bfloat16(src[tp]);
}

// ---- main: implicit GEMM over taps; K = 9 taps * 128 ci = 1152 = 36 stages of 32.
// LDS: 4 buffers x (A 8KB + B 8KB) = 64KB. Rows are 64 B (4 segs of 16 B).
// Swizzle: LDS seg s of row R holds global seg s ^ ((R>>1)&3)  (residual 2-way = free).
//   staging source seg  = (l&3) ^ ((l>>3)&3)            (lane-only)
//   read seg for quad q = q ^ ((l15>>1)&3)              (lane-only)
__global__ __launch_bounds__(256) void conv_main(
    const char* __restrict__ xpb,
    const char* __restrict__ wtb,
    const float* __restrict__ bias,
    float* __restrict__ out)
{
    __shared__ __align__(16) char L[65536];  // A: [0,32768), B: [32768,65536)

    const int tid  = threadIdx.x;
    const int l    = tid & 63;
    const int wv   = tid >> 6;
    const int wm   = wv & 1;
    const int wn   = wv >> 1;
    const int l15  = l & 15;
    const int quad = l >> 4;

    // XCD-pair swizzle: blocks idx and idx+8 (same XCD under %8 round-robin) share bn.
    const int idx = blockIdx.x;
    const int bm  = (idx >> 3) & 1;
    const int bn  = (idx >> 4) * 8 + (idx & 7);
    const int pbase  = bn * 128;
    const int cobase = bm * 128;

    // staging: chunk c = wv*2+j covers rows c*16 .. c*16+15 (16 rows x 64 B = 1 KB);
    // lane -> row c*16 + (l>>2), LDS seg l&3, global seg (l&3)^((l>>3)&3).
    const int gseg = (l & 3) ^ ((l >> 3) & 3);
    unsigned aoff[2], boff[2];
    #pragma unroll
    for (int j = 0; j < 2; ++j) {
        const int c   = wv * 2 + j;
        const int row = c * 16 + (l >> 2);
        aoff[j] = (unsigned)((cobase + row) * 256 + gseg * 16);
        const int p   = pbase + row;
        const int n   = p / HW;
        const int rem = p - n * HW;
        const int y   = rem / WW;
        const int x   = rem - y * WW;
        boff[j] = (unsigned)((n * XPIX + y * XPW + x) * 256 + gseg * 16);
    }
    const int segoff = (quad ^ ((l15 >> 1) & 3)) << 4;  // lane-only read swizzle

    f32x4 acc[4][4];
    #pragma unroll
    for (int i = 0; i < 4; ++i)
        #pragma unroll
        for (int j = 0; j < 4; ++j)
            acc[i][j] = (f32x4){0.f, 0.f, 0.f, 0.f};

    // stage s: tap t = s>>2, ci-quarter kq = s&3 (bytes kq*64 within each 256 B ci-row)
    auto STAGE = [&](int s, int bufw) {
        const int t  = s >> 2;
        const int kq = s & 3;
        const int r  = t / 3;
        const int sx = t - 3 * r;
        const unsigned wo = (unsigned)(t * (COUT * CIN * 2) + kq * 64);
        const unsigned bo = (unsigned)((r * XPW + sx) * 256 + kq * 64);
        char* Ab = L + bufw * 8192;
        char* Bb = L + 32768 + bufw * 8192;
        #pragma unroll
        for (int j = 0; j < 2; ++j) {
            const int c = wv * 2 + j;
            GLD16(wtb + wo + aoff[j], Ab + c * 1024);
            GLD16(xpb + bo + boff[j], Bb + c * 1024);
        }
    };

    // prologue: 3 stages in flight (12 loads/thread)
    STAGE(0, 0);
    STAGE(1, 1);
    STAGE(2, 2);

    #pragma unroll
    for (int s = 0; s < 36; ++s) {
        // wait oldest 4 loads (stage s) -> 8 stay in flight across the barrier
        asm volatile("s_waitcnt vmcnt(8)" ::: "memory");
        __builtin_amdgcn_s_barrier();
        asm volatile("" ::: "memory");   // fence: no LDS-read hoisting above barrier

        // issue stage s+3 into the buffer freed by stage s-1 (dummy re-stage of 35
        // for the last 3 iterations keeps vmcnt arithmetic uniform; dead buffer).
        STAGE((s + 3 < 36) ? s + 3 : 35, (s + 3) & 3);

        const char* Ab = L + (s & 3) * 8192;
        const char* Bb = L + 32768 + (s & 3) * 8192;
        bf16x8 af[4], bfr[4];
        #pragma unroll
        for (int mt = 0; mt < 4; ++mt)
            af[mt] = *(const bf16x8*)(Ab + (wm * 64 + mt * 16 + l15) * 64 + segoff);
        #pragma unroll
        for (int nt = 0; nt < 4; ++nt)
            bfr[nt] = *(const bf16x8*)(Bb + (wn * 64 + nt * 16 + l15) * 64 + segoff);

        __builtin_amdgcn_s_setprio(1);
        #pragma unroll
        for (int mt = 0; mt < 4; ++mt)
            #pragma unroll
            for (int nt = 0; nt < 4; ++nt)
                acc[mt][nt] = __builtin_amdgcn_mfma_f32_16x16x32_bf16(
                    af[mt], bfr[nt], acc[mt][nt], 0, 0, 0);
        __builtin_amdgcn_s_setprio(0);
    }

    // drain the trailing dummy loads before LDS goes out of scope
    asm volatile("s_waitcnt vmcnt(0)" ::: "memory");

    // epilogue: D[m = quad*4+reg][n = l15]; out (N, C_out, H, W)
    #pragma unroll
    for (int nt = 0; nt < 4; ++nt) {
        const int pp = pbase + wn * 64 + nt * 16 + l15;
        const int n2 = pp / HW;
        const int r2 = pp - n2 * HW;
        float* ob = out + (size_t)n2 * (COUT * HW) + r2;
        #pragma unroll
        for (int mt = 0; mt < 4; ++mt) {
            const int co = cobase + wm * 64 + mt * 16 + quad * 4;
            const float4 bv = *(const float4*)(bias + co);
            f32x4 a = acc[mt][nt];
            ob[(size_t)(co + 0) * HW] = a[0] + bv.x;
            ob[(size_t)(co + 1) * HW] = a[1] + bv.y;
            ob[(size_t)(co + 2) * HW] = a[2] + bv.z;
            ob[(size_t)(co + 3) * HW] = a[3] + bv.w;
        }
    }
}

extern "C" void kernel_launch(void* const* d_in, const int* in_sizes, int n_in,
                              void* d_out, int out_size, void* d_ws, size_t ws_size,
                              hipStream_t stream) {
    const float* x = (const float*)d_in[0];
    const float* w = (const float*)d_in[1];
    const float* b = (const float*)d_in[2];
    char* ws = (char*)d_ws;                      // needs >= 28.2 MB
    __hip_bfloat16* xp = (__hip_bfloat16*)ws;
    __hip_bfloat16* wt = (__hip_bfloat16*)(ws + WT_OFF);

    prep_x<<<dim3(NIMG * HH), dim3(128), 0, stream>>>(x, xp);
    prep_w<<<dim3(128), dim3(256), 0, stream>>>(w, wt);
    conv_main<<<dim3((NP / 128) * 2), dim3(256), 0, stream>>>(
        (const char*)xp, (const char*)wt, b, (float*)d_out);
}

// Round 6
// 208.046 us; speedup vs baseline: 1.0252x; 1.0252x over previous
//
#include <hip/hip_runtime.h>
#include <hip/hip_bf16.h>

// Conv2d 3x3 s1p1: x(32,128,56,56) f32, w(256,128,3,3) f32, bias(256) -> (32,256,56,56) f32.
// R5 (3rd submit; rounds 4-5 hit GPUAcquisitionTimeout — no data):
// revert R4's fine-phase pipeline (regressed 81->88 us; 4-wave/128-tile fine phases
// lose to barrier overhead — matches m232/m196). conv_main now = m97-proven config:
// BK=64, 32 KB LDS single-buffered, 2-sync-per-stage loop, 18 stages, NO setprio,
// NO raw barriers. LDS 64KB->32KB raises residency 2->5 blocks/CU; implicit wave-level
// overlap across blocks hides the barrier drain (m97: 912 TF with 3 blocks/CU).
// Swizzle re-derived for 128 B rows (8 segs of 16 B):
//   LDS seg of row R holds global seg s^(R&7); store side lane-only: gseg=(l&7)^(l>>3);
//   read side: seg_lds = kslice ^ (l15&7) — 8 consecutive lanes -> 8 distinct segs.
// prep_x / prep_w unchanged.

#define CIN   128
#define HH    56
#define WW    56
#define COUT  256
#define HW    3136
#define NIMG  32
#define NP    (NIMG * HW)            // 100352 = 784 * 128
#define XPW   58
#define XPIX  (XPW * XPW)            // 3364
#define XPAD_BYTES (NIMG * XPIX * CIN * 2)   // 27,566,080
#define WT_OFF     XPAD_BYTES

typedef __bf16 bf16x8 __attribute__((ext_vector_type(8)));
typedef float  f32x4  __attribute__((ext_vector_type(4)));

#define GLD16(g, l) __builtin_amdgcn_global_load_lds( \
    (const __attribute__((address_space(1))) void*)(g), \
    (__attribute__((address_space(3))) void*)(l), 16, 0, 0)

__device__ __forceinline__ unsigned pack_bf16(float a, float b) {
    return (__float_as_uint(b) & 0xFFFF0000u) | (__float_as_uint(a) >> 16);
}

// ---- pre-pass 1: x NCHW f32 -> xpad NHWC bf16 with 1-px halo; writes own halo zeros.
__global__ __launch_bounds__(128) void prep_x(const float* __restrict__ x,
                                              __hip_bfloat16* __restrict__ xp) {
    __shared__ unsigned short t[HH * CIN];   // [x][ci], 14336 B
    const int b  = blockIdx.x;               // 32*56
    const int n  = b / HH;
    const int y  = b - n * HH;
    const int ci = threadIdx.x;              // 0..127

    const float* src = x + ((size_t)(n * CIN + ci) * HW) + y * WW;
    #pragma unroll
    for (int j = 0; j < 14; ++j) {           // 56 floats, per-lane contiguous stream
        const float4 v = ((const float4*)src)[j];
        t[(4 * j + 0) * CIN + ci] = (unsigned short)(__float_as_uint(v.x) >> 16);
        t[(4 * j + 1) * CIN + ci] = (unsigned short)(__float_as_uint(v.y) >> 16);
        t[(4 * j + 2) * CIN + ci] = (unsigned short)(__float_as_uint(v.z) >> 16);
        t[(4 * j + 3) * CIN + ci] = (unsigned short)(__float_as_uint(v.w) >> 16);
    }

    const uint4 z = make_uint4(0, 0, 0, 0);
    if (ci < 32) {
        const int side = ci >> 4;            // 0 = x'=0, 1 = x'=57
        const int j    = ci & 15;
        ((uint4*)(xp + ((size_t)n * XPIX + (y + 1) * XPW + side * 57) * CIN))[j] = z;
    }
    if (y == 0)
        for (int j = ci; j < 928; j += 128)  // row 0: 58*128 bf16 = 928 uint4
            ((uint4*)(xp + (size_t)n * XPIX * CIN))[j] = z;
    if (y == HH - 1)
        for (int j = ci; j < 928; j += 128)  // row 57
            ((uint4*)(xp + ((size_t)n * XPIX + 57 * XPW) * CIN))[j] = z;

    __syncthreads();

    uint4* dst = (uint4*)(xp + ((size_t)n * XPIX + (y + 1) * XPW + 1) * CIN);
    const uint4* lsrc = (const uint4*)t;
    #pragma unroll
    for (int j = 0; j < 7; ++j)
        dst[j * 128 + ci] = lsrc[j * 128 + ci];
}

// ---- pre-pass 2: w (co,ci,3,3) f32 -> Wt[tap][co][ci] bf16
__global__ __launch_bounds__(256) void prep_w(const float* __restrict__ w,
                                              __hip_bfloat16* __restrict__ wt) {
    const int co = blockIdx.x * 2 + (threadIdx.x >> 7);
    const int ci = threadIdx.x & 127;
    const float* src = w + (size_t)(co * CIN + ci) * 9;
    #pragma unroll
    for (int tp = 0; tp < 9; ++tp)
        wt[(size_t)tp * (COUT * CIN) + co * CIN + ci] = __float2bfloat16(src[tp]);
}

// ---- main: implicit GEMM over taps; K = 9 taps * 128 ci = 1152 = 18 stages of 64.
// LDS: A 16KB + B 16KB = 32 KB single-buffered -> 5 blocks/CU. Rows are 128 B (8 segs).
__global__ __launch_bounds__(256) void conv_main(
    const char* __restrict__ xpb,
    const char* __restrict__ wtb,
    const float* __restrict__ bias,
    float* __restrict__ out)
{
    __shared__ __align__(16) char L[32768];  // A: [0,16384), B: [16384,32768)

    const int tid  = threadIdx.x;
    const int l    = tid & 63;
    const int wv   = tid >> 6;
    const int wm   = wv & 1;
    const int wn   = wv >> 1;
    const int l15  = l & 15;
    const int quad = l >> 4;

    // XCD-pair swizzle: blocks idx and idx+8 (same XCD under %8 round-robin) share bn.
    const int idx = blockIdx.x;
    const int bm  = (idx >> 3) & 1;
    const int bn  = (idx >> 4) * 8 + (idx & 7);
    const int pbase  = bn * 128;
    const int cobase = bm * 128;

    // staging: chunk c = wv*4+j covers rows c*8..c*8+7 (8 rows x 128 B = 1 KB);
    // lane -> row c*8 + (l>>3), LDS seg l&7, global seg (l&7)^(l>>3)  (lane-only).
    const int gseg = (l & 7) ^ (l >> 3);
    unsigned aoff[4], boff[4];
    #pragma unroll
    for (int j = 0; j < 4; ++j) {
        const int c   = wv * 4 + j;
        const int row = c * 8 + (l >> 3);
        aoff[j] = (unsigned)((cobase + row) * 256 + gseg * 16);
        const int p   = pbase + row;
        const int n   = p / HW;
        const int rem = p - n * HW;
        const int y   = rem / WW;
        const int x   = rem - y * WW;
        boff[j] = (unsigned)((n * XPIX + y * XPW + x) * 256 + gseg * 16);
    }

    f32x4 acc[4][4];
    #pragma unroll
    for (int i = 0; i < 4; ++i)
        #pragma unroll
        for (int j = 0; j < 4; ++j)
            acc[i][j] = (f32x4){0.f, 0.f, 0.f, 0.f};

    // stage s: tap t = s>>1, ci-half h = s&1 (bytes h*128 within each 256 B ci-row)
    #pragma unroll
    for (int s = 0; s < 18; ++s) {
        const int t  = s >> 1;
        const int h  = s & 1;
        const int r  = t / 3;
        const int sx = t - 3 * r;
        const unsigned wo = (unsigned)(t * (COUT * CIN * 2) + h * 128);   // Wt tap plane
        const unsigned bo = (unsigned)((r * XPW + sx) * 256 + h * 128);   // xpad tap shift

        __syncthreads();
        #pragma unroll
        for (int j = 0; j < 4; ++j) {
            const int c = wv * 4 + j;
            GLD16(wtb + wo + aoff[j], L + c * 1024);
            GLD16(xpb + bo + boff[j], L + 16384 + c * 1024);
        }
        __syncthreads();

        #pragma unroll
        for (int kg = 0; kg < 2; ++kg) {
            bf16x8 af[4], bfr[4];
            const int segoff = ((kg * 4 + quad) ^ (l15 & 7)) << 4;
            #pragma unroll
            for (int mt = 0; mt < 4; ++mt) {
                const int row = wm * 64 + mt * 16 + l15;
                af[mt] = *(const bf16x8*)(L + row * 128 + segoff);
            }
            #pragma unroll
            for (int nt = 0; nt < 4; ++nt) {
                const int row = wn * 64 + nt * 16 + l15;
                bfr[nt] = *(const bf16x8*)(L + 16384 + row * 128 + segoff);
            }
            #pragma unroll
            for (int mt = 0; mt < 4; ++mt)
                #pragma unroll
                for (int nt = 0; nt < 4; ++nt)
                    acc[mt][nt] = __builtin_amdgcn_mfma_f32_16x16x32_bf16(
                        af[mt], bfr[nt], acc[mt][nt], 0, 0, 0);
        }
    }

    // epilogue: D[m = quad*4+reg][n = l15]; out (N, C_out, H, W)
    #pragma unroll
    for (int nt = 0; nt < 4; ++nt) {
        const int pp = pbase + wn * 64 + nt * 16 + l15;
        const int n2 = pp / HW;
        const int r2 = pp - n2 * HW;
        float* ob = out + (size_t)n2 * (COUT * HW) + r2;
        #pragma unroll
        for (int mt = 0; mt < 4; ++mt) {
            const int co = cobase + wm * 64 + mt * 16 + quad * 4;
            const float4 bv = *(const float4*)(bias + co);
            f32x4 a = acc[mt][nt];
            ob[(size_t)(co + 0) * HW] = a[0] + bv.x;
            ob[(size_t)(co + 1) * HW] = a[1] + bv.y;
            ob[(size_t)(co + 2) * HW] = a[2] + bv.z;
            ob[(size_t)(co + 3) * HW] = a[3] + bv.w;
        }
    }
}

extern "C" void kernel_launch(void* const* d_in, const int* in_sizes, int n_in,
                              void* d_out, int out_size, void* d_ws, size_t ws_size,
                              hipStream_t stream) {
    const float* x = (const float*)d_in[0];
    const float* w = (const float*)d_in[1];
    const float* b = (const float*)d_in[2];
    char* ws = (char*)d_ws;                      // needs >= 28.2 MB
    __hip_bfloat16* xp = (__hip_bfloat16*)ws;
    __hip_bfloat16* wt = (__hip_bfloat16*)(ws + WT_OFF);

    prep_x<<<dim3(NIMG * HH), dim3(128), 0, stream>>>(x, xp);
    prep_w<<<dim3(128), dim3(256), 0, stream>>>(w, wt);
    conv_main<<<dim3((NP / 128) * 2), dim3(256), 0, stream>>>(
        (const char*)xp, (const char*)wt, b, (float*)d_out);
}